// Round 2
// baseline (602.447 us; speedup 1.0000x reference)
//
#include <hip/hip_runtime.h>
#include <math.h>

#define TPB 256

constexpr int LSEQ = 2048;
constexpr int FEAT = 512;
constexpr int NH = 8;
constexpr int DM = 512;   // NH * HEAD_DIM
constexpr int NB = 2;

// ---------------------------------------------------------------- pos table
// posT[f][l], layout (F, L) to match inputs (B, F, L) for coalesced staging.
__global__ __launch_bounds__(TPB) void pos_kernel(float* __restrict__ posT) {
  int idx = blockIdx.x * TPB + threadIdx.x;   // f*LSEQ + l
  int l = idx & (LSEQ - 1);
  int f = idx >> 11;
  int i = f >> 1;
  double t = exp((double)i * (9.210340371976184 / 256.0));  // 10000^(i/256)
  float ang = (float)((double)l / t);
  posT[idx] = (f & 1) ? cosf(ang) : sinf(ang);
}

// ---------------------------------------------------------------- projection
// C[r, c], r in [0,4096) (= b*2048 + l), c in [0,1024): c<512 -> q else k.
// A[r][f] = inputs[b][f][l] + posT[f][l];  C = A @ W^T + bias
__global__ __launch_bounds__(TPB) void proj_kernel(
    const float* __restrict__ x, const float* __restrict__ posT,
    const float* __restrict__ Wq, const float* __restrict__ bq,
    const float* __restrict__ Wk, const float* __restrict__ bk,
    float* __restrict__ qbuf, float* __restrict__ kbuf) {
  __shared__ float As[32][64];   // [kk][m]
  __shared__ float Ws[32][68];   // [kk][n], padded (store-conflict relief)
  const int t = threadIdx.x;
  const int bx = blockIdx.x;      // 0..15 col tile
  const int by = blockIdx.y;      // 0..63 row tile
  const int c0 = bx * 64;
  const int r0 = by * 64;
  const int b = r0 >> 11;
  const int l0 = r0 & (LSEQ - 1);
  const float* W = (c0 < DM) ? Wq : Wk;
  const float* bias = (c0 < DM) ? bq : bk;
  float* out = (c0 < DM) ? qbuf : kbuf;
  const int cw0 = c0 & (DM - 1);
  const int ty = t >> 4, tx = t & 15;
  float acc[4][4] = {};
  for (int f0 = 0; f0 < FEAT; f0 += 32) {
#pragma unroll
    for (int rep = 0; rep < 2; ++rep) {   // stage A tile (transposed, coalesced over l)
      int f4i = rep * 256 + t;
      int kk = f4i >> 4, m4 = f4i & 15;
      float4 xv = *(const float4*)(x + (size_t)b * FEAT * LSEQ + (size_t)(f0 + kk) * LSEQ + l0 + m4 * 4);
      float4 pv = *(const float4*)(posT + (size_t)(f0 + kk) * LSEQ + l0 + m4 * 4);
      float4 v = make_float4(xv.x + pv.x, xv.y + pv.y, xv.z + pv.z, xv.w + pv.w);
      *(float4*)&As[kk][m4 * 4] = v;
    }
#pragma unroll
    for (int rep = 0; rep < 2; ++rep) {   // stage W tile -> Ws[kk][n]
      int f4i = rep * 256 + t;
      int n = f4i >> 3, k4 = f4i & 7;
      float4 wv = *(const float4*)(W + (size_t)(cw0 + n) * FEAT + f0 + k4 * 4);
      Ws[k4 * 4 + 0][n] = wv.x;
      Ws[k4 * 4 + 1][n] = wv.y;
      Ws[k4 * 4 + 2][n] = wv.z;
      Ws[k4 * 4 + 3][n] = wv.w;
    }
    __syncthreads();
#pragma unroll 8
    for (int kk = 0; kk < 32; ++kk) {
      float4 a = *(const float4*)&As[kk][ty * 4];
      float4 bb = *(const float4*)&Ws[kk][tx * 4];
      float av[4] = {a.x, a.y, a.z, a.w};
      float bv[4] = {bb.x, bb.y, bb.z, bb.w};
#pragma unroll
      for (int i = 0; i < 4; ++i)
#pragma unroll
        for (int j = 0; j < 4; ++j) acc[i][j] += av[i] * bv[j];
    }
    __syncthreads();
  }
  float bv4[4];
#pragma unroll
  for (int j = 0; j < 4; ++j) bv4[j] = bias[cw0 + tx * 4 + j];
#pragma unroll
  for (int i = 0; i < 4; ++i) {
    int r = r0 + ty * 4 + i;
    float4 v = make_float4(acc[i][0] + bv4[0], acc[i][1] + bv4[1],
                           acc[i][2] + bv4[2], acc[i][3] + bv4[3]);
    *(float4*)(out + (size_t)r * DM + cw0 + tx * 4) = v;
  }
}

// ---------------------------------------------------------------- scores
// Writes P = exp(q.k/8) into attn region (layout (b,q,kk,h)) + partial row
// sums lpart[b][kkblk][q][h]. No max-subtraction needed: |s| <= |q||k|/8 < ~16.
__global__ __launch_bounds__(TPB) void score_kernel(
    const float* __restrict__ qbuf, const float* __restrict__ kbuf,
    float* __restrict__ P, float* __restrict__ lpart) {
  __shared__ float Qs[16 * 576];   // [q][h*72 + d], padded strides (conflict-free)
  __shared__ float Ps[16 * 260];   // [q][kk*8+h], pad keeps 16B align per row
  __shared__ float red[16 * 32];   // [q][wave][h]
  const int t = threadIdx.x;
  const int bid = blockIdx.x;
  const int b = bid >> 10;
  const int kkblk = (bid & 1023) >> 4;   // 0..63  (32 kk each)
  const int qgrp = bid & 15;             // 0..15  (128 q each)
  const int h = t & 7;
  const int kkl = t >> 3;                // 0..31
  const int kk = kkblk * 32 + kkl;
  const int w = t >> 6;
  const int lane = t & 63;
  float4 kreg[16];
  {
    const float* kp = kbuf + ((size_t)(b * LSEQ + kk)) * DM + h * 64;
#pragma unroll
    for (int d4 = 0; d4 < 16; ++d4) kreg[d4] = *(const float4*)(kp + d4 * 4);
  }
  for (int qs = 0; qs < 8; ++qs) {
    const int q0 = qgrp * 128 + qs * 16;
#pragma unroll
    for (int rep = 0; rep < 8; ++rep) {    // stage 16 q-rows
      int f4i = rep * 256 + t;
      int row = f4i >> 7, c4 = f4i & 127;
      float4 v = *(const float4*)(qbuf + ((size_t)(b * LSEQ + q0 + row)) * DM + c4 * 4);
      int hh = c4 >> 4, d4 = c4 & 15;
      *(float4*)&Qs[row * 576 + hh * 72 + d4 * 4] = v;
    }
    __syncthreads();
    for (int q = 0; q < 16; ++q) {
      const float* qrow = &Qs[q * 576 + h * 72];
      float4 s4 = make_float4(0.f, 0.f, 0.f, 0.f);
#pragma unroll
      for (int d4 = 0; d4 < 16; ++d4) {
        float4 qv = *(const float4*)(qrow + d4 * 4);
        s4.x += qv.x * kreg[d4].x;
        s4.y += qv.y * kreg[d4].y;
        s4.z += qv.z * kreg[d4].z;
        s4.w += qv.w * kreg[d4].w;
      }
      float s = (s4.x + s4.y) + (s4.z + s4.w);
      float p = __expf(s * 0.125f);
      Ps[q * 260 + t] = p;
      float ps = p;
      ps += __shfl_xor(ps, 8);
      ps += __shfl_xor(ps, 16);
      ps += __shfl_xor(ps, 32);
      if (lane < 8) red[(q * 4 + w) * 8 + lane] = ps;  // lane==h here
    }
    __syncthreads();
    if (t < 128) {
      int q = t >> 3, hh = t & 7;
      float s = red[(q * 4 + 0) * 8 + hh] + red[(q * 4 + 1) * 8 + hh] +
                red[(q * 4 + 2) * 8 + hh] + red[(q * 4 + 3) * 8 + hh];
      lpart[((size_t)(b * 64 + kkblk) * LSEQ + (q0 + q)) * 8 + hh] = s;
    }
#pragma unroll
    for (int rep = 0; rep < 4; ++rep) {   // coalesced P write-back: 16 q x 64 float4
      int f4i = rep * 256 + t;
      int q = f4i >> 6, u = f4i & 63;
      float4 v = *(const float4*)&Ps[q * 260 + u * 4];
      *(float4*)(P + ((size_t)(b * LSEQ + q0 + q)) * (LSEQ * NH) + kkblk * 256 + u * 4) = v;
    }
    __syncthreads();
  }
}

// ---------------------------------------------------------------- softmax-scale + PV
// Per (b, 16 q-rows, kk-split): scale P in place (-> final attn, coalesced),
// accumulate dist partial = sum_kk attn * k. K tile swizzled in LDS.
__global__ __launch_bounds__(TPB) void pv_kernel(
    const float* __restrict__ kbuf, const float* __restrict__ lpart,
    float* __restrict__ attn, float* __restrict__ distbase, int log2split) {
  __shared__ float Ks[16 * 576];  // [kk][p(c)], p(c) = c + 4*(c>>5)
  __shared__ float Pa[16 * 132];  // [q][kk*8+h]
  __shared__ float linv[128];
  const int t = threadIdx.x;
  const int bid = blockIdx.x;
  const int nsplit = 1 << log2split;
  const int sp = bid & (nsplit - 1);
  const int qt = (bid >> log2split) & 127;
  const int b = bid >> (7 + log2split);
  const int q0 = qt * 16;
  if (t < 128) {   // softmax denominators (coalesced over (q,h))
    int q = t >> 3, hh = t & 7;
    float s = 0.f;
#pragma unroll 8
    for (int i = 0; i < 64; ++i)
      s += lpart[((size_t)(b * 64 + i) * LSEQ + (q0 + q)) * 8 + hh];
    linv[t] = 1.0f / s;
  }
  __syncthreads();
  const int qg = t >> 5;                         // 0..7
  const int cs = t & 31;                         // 0..31 (16 cols each)
  const int pofs = cs * 16 + 4 * (cs >> 1);      // swizzled col offset
  const int hsel = cs >> 2;                      // head of this col block
  float acc[2][16] = {};
  const int nch = 128 >> log2split;
  const int ch0 = sp * nch;
  for (int ci = 0; ci < nch; ++ci) {
    const int ch = ch0 + ci;
#pragma unroll
    for (int rep = 0; rep < 8; ++rep) {   // stage K tile (16 kk x 512), swizzled
      int f4i = rep * 256 + t;
      int kk = f4i >> 7, c4 = f4i & 127;
      float4 v = *(const float4*)(kbuf + ((size_t)(b * LSEQ + ch * 16 + kk)) * DM + c4 * 4);
      int c = c4 * 4;
      *(float4*)&Ks[kk * 576 + c + 4 * (c >> 5)] = v;
    }
#pragma unroll
    for (int rep = 0; rep < 2; ++rep) {   // read P, scale, write attn, stash in LDS
      int f4i = rep * 256 + t;
      int q = f4i >> 5, u = f4i & 31;
      float* gp = attn + ((size_t)(b * LSEQ + q0 + q)) * (LSEQ * NH) + ch * 128 + u * 4;
      float4 v = *(const float4*)gp;
      int hb = (u & 1) * 4;
      v.x *= linv[q * 8 + hb + 0];
      v.y *= linv[q * 8 + hb + 1];
      v.z *= linv[q * 8 + hb + 2];
      v.w *= linv[q * 8 + hb + 3];
      *(float4*)gp = v;
      *(float4*)&Pa[q * 132 + u * 4] = v;
    }
    __syncthreads();
#pragma unroll 2
    for (int kk = 0; kk < 16; ++kk) {
      const float* krow = &Ks[kk * 576 + pofs];
      float4 kf0 = *(const float4*)(krow + 0);
      float4 kf1 = *(const float4*)(krow + 4);
      float4 kf2 = *(const float4*)(krow + 8);
      float4 kf3 = *(const float4*)(krow + 12);
#pragma unroll
      for (int qi = 0; qi < 2; ++qi) {
        float a = Pa[(qg * 2 + qi) * 132 + kk * 8 + hsel];
        acc[qi][0]  += a * kf0.x;  acc[qi][1]  += a * kf0.y;
        acc[qi][2]  += a * kf0.z;  acc[qi][3]  += a * kf0.w;
        acc[qi][4]  += a * kf1.x;  acc[qi][5]  += a * kf1.y;
        acc[qi][6]  += a * kf1.z;  acc[qi][7]  += a * kf1.w;
        acc[qi][8]  += a * kf2.x;  acc[qi][9]  += a * kf2.y;
        acc[qi][10] += a * kf2.z;  acc[qi][11] += a * kf2.w;
        acc[qi][12] += a * kf3.x;  acc[qi][13] += a * kf3.y;
        acc[qi][14] += a * kf3.z;  acc[qi][15] += a * kf3.w;
      }
    }
    __syncthreads();
  }
  float* distp = distbase + (size_t)sp * (NB * LSEQ * DM);
#pragma unroll
  for (int qi = 0; qi < 2; ++qi) {
    int q = q0 + qg * 2 + qi;
    float* dp = distp + ((size_t)(b * LSEQ + q)) * DM + cs * 16;
#pragma unroll
    for (int j = 0; j < 4; ++j)
      *(float4*)(dp + j * 4) = make_float4(acc[qi][j * 4 + 0], acc[qi][j * 4 + 1],
                                           acc[qi][j * 4 + 2], acc[qi][j * 4 + 3]);
  }
}

// ---------------------------------------------------------------- combine dist partials
__global__ __launch_bounds__(TPB) void combine_kernel(const float* __restrict__ p,
                                                      float* __restrict__ dist) {
  int i4 = blockIdx.x * TPB + threadIdx.x;   // 0..524287 (float4s)
  const int N4 = (NB * LSEQ * DM) / 4;
  const float4* p4 = (const float4*)p;
  float4 a = p4[i4], b1 = p4[N4 + i4], c = p4[2 * N4 + i4], d = p4[3 * N4 + i4];
  ((float4*)dist)[i4] = make_float4(a.x + b1.x + c.x + d.x, a.y + b1.y + c.y + d.y,
                                    a.z + b1.z + c.z + d.z, a.w + b1.w + c.w + d.w);
}

extern "C" void kernel_launch(void* const* d_in, const int* in_sizes, int n_in,
                              void* d_out, int out_size, void* d_ws, size_t ws_size,
                              hipStream_t stream) {
  const float* x  = (const float*)d_in[0];
  const float* Wq = (const float*)d_in[1];
  const float* bq = (const float*)d_in[2];
  const float* Wk = (const float*)d_in[3];
  const float* bk = (const float*)d_in[4];
  // d_in[5], d_in[6] (Wv, bv) intentionally unused: reference discards v.
  float* out = (float*)d_out;
  float* dist = out;                                   // (B, L, 512)
  float* attn = out + (size_t)NB * LSEQ * DM;          // (B, L, L, H)
  float* ws = (float*)d_ws;
  float* posT  = ws;               // 1,048,576 floats
  float* qbuf  = ws + 1048576;     // 2,097,152
  float* kbuf  = ws + 3145728;     // 2,097,152
  float* lpart = ws + 5242880;     // 2,097,152
  float* distp = ws + 7340032;     // 4 * 2,097,152 (only if ws allows)
  const size_t need_split = (size_t)(7340032 + 4 * 2097152) * sizeof(float);
  const int log2split = (ws_size >= need_split) ? 2 : 0;

  pos_kernel<<<4096, TPB, 0, stream>>>(posT);
  dim3 pg(16, 64);
  proj_kernel<<<pg, TPB, 0, stream>>>(x, posT, Wq, bq, Wk, bk, qbuf, kbuf);
  score_kernel<<<2048, TPB, 0, stream>>>(qbuf, kbuf, attn, lpart);
  if (log2split) {
    pv_kernel<<<NB * 128 * 4, TPB, 0, stream>>>(kbuf, lpart, attn, distp, 2);
    combine_kernel<<<2048, TPB, 0, stream>>>(distp, dist);
  } else {
    pv_kernel<<<NB * 128, TPB, 0, stream>>>(kbuf, lpart, attn, dist, 0);
  }
}

// Round 3
// 251.870 us; speedup vs baseline: 2.3919x; 2.3919x over previous
//
#include <hip/hip_runtime.h>
#include <math.h>

constexpr int LSEQ = 2048;
constexpr int FEAT = 512;
constexpr int NH = 8;
constexpr int DM = 512;   // NH * HEAD_DIM
constexpr int NB = 2;

typedef __bf16 bf16x8 __attribute__((ext_vector_type(8)));
typedef unsigned short u16x8 __attribute__((ext_vector_type(8)));
typedef float f32x4 __attribute__((ext_vector_type(4)));

struct alignas(8) us4 { unsigned short x, y, z, w; };

__device__ inline f32x4 mfma16(u16x8 a, u16x8 b, f32x4 c) {
  return __builtin_amdgcn_mfma_f32_16x16x32_bf16(
      __builtin_bit_cast(bf16x8, a), __builtin_bit_cast(bf16x8, b), c, 0, 0, 0);
}
__device__ inline unsigned short f2bf(float x) {   // round-to-nearest-even
  unsigned u = __float_as_uint(x);
  return (unsigned short)((u + 0x7fffu + ((u >> 16) & 1u)) >> 16);
}
__device__ inline u16x8 ldbf8(const unsigned short* p) {
  return *reinterpret_cast<const u16x8*>(p);
}

// ---------------------------------------------------------------- pos table
__global__ __launch_bounds__(256) void pos_kernel(float* __restrict__ posT) {
  int idx = blockIdx.x * 256 + threadIdx.x;   // f*LSEQ + l
  int l = idx & (LSEQ - 1);
  int f = idx >> 11;
  int i = f >> 1;
  double t = exp((double)i * (9.210340371976184 / 256.0));  // 10000^(i/256)
  float ang = (float)((double)l / t);
  posT[idx] = (f & 1) ? cosf(ang) : sinf(ang);
}

// ---------------------------------------------------------------- projection
// fp32 GEMM core (accuracy), epilogue emits bf16 q/k + bf16 kT[b][d][kk].
__global__ __launch_bounds__(256) void proj_kernel(
    const float* __restrict__ x, const float* __restrict__ posT,
    const float* __restrict__ Wq, const float* __restrict__ bq,
    const float* __restrict__ Wk, const float* __restrict__ bk,
    unsigned short* __restrict__ qb, unsigned short* __restrict__ kb,
    unsigned short* __restrict__ kT) {
  __shared__ float As[32][64];
  __shared__ float Ws[32][68];
  const int t = threadIdx.x;
  const int bx = blockIdx.x;      // 0..15 col tile
  const int by = blockIdx.y;      // 0..63 row tile
  const int c0 = bx * 64;
  const int r0 = by * 64;
  const int b = r0 >> 11;
  const int l0 = r0 & (LSEQ - 1);
  const float* W = (c0 < DM) ? Wq : Wk;
  const float* bias = (c0 < DM) ? bq : bk;
  const int cw0 = c0 & (DM - 1);
  const int ty = t >> 4, tx = t & 15;
  float acc[4][4] = {};
  for (int f0 = 0; f0 < FEAT; f0 += 32) {
#pragma unroll
    for (int rep = 0; rep < 2; ++rep) {
      int f4i = rep * 256 + t;
      int kk = f4i >> 4, m4 = f4i & 15;
      float4 xv = *(const float4*)(x + (size_t)b * FEAT * LSEQ + (size_t)(f0 + kk) * LSEQ + l0 + m4 * 4);
      float4 pv = *(const float4*)(posT + (size_t)(f0 + kk) * LSEQ + l0 + m4 * 4);
      *(float4*)&As[kk][m4 * 4] = make_float4(xv.x + pv.x, xv.y + pv.y, xv.z + pv.z, xv.w + pv.w);
    }
#pragma unroll
    for (int rep = 0; rep < 2; ++rep) {
      int f4i = rep * 256 + t;
      int n = f4i >> 3, k4 = f4i & 7;
      float4 wv = *(const float4*)(W + (size_t)(cw0 + n) * FEAT + f0 + k4 * 4);
      Ws[k4 * 4 + 0][n] = wv.x;
      Ws[k4 * 4 + 1][n] = wv.y;
      Ws[k4 * 4 + 2][n] = wv.z;
      Ws[k4 * 4 + 3][n] = wv.w;
    }
    __syncthreads();
#pragma unroll 8
    for (int kk = 0; kk < 32; ++kk) {
      float4 a = *(const float4*)&As[kk][ty * 4];
      float4 bb = *(const float4*)&Ws[kk][tx * 4];
      float av[4] = {a.x, a.y, a.z, a.w};
      float bv[4] = {bb.x, bb.y, bb.z, bb.w};
#pragma unroll
      for (int i = 0; i < 4; ++i)
#pragma unroll
        for (int j = 0; j < 4; ++j) acc[i][j] += av[i] * bv[j];
    }
    __syncthreads();
  }
  float bv4[4];
#pragma unroll
  for (int j = 0; j < 4; ++j) bv4[j] = bias[cw0 + tx * 4 + j];
#pragma unroll
  for (int i = 0; i < 4; ++i)
#pragma unroll
    for (int j = 0; j < 4; ++j) acc[i][j] += bv4[j];

  const int isK = (c0 >= DM);
  unsigned short* outb = isK ? kb : qb;
#pragma unroll
  for (int i = 0; i < 4; ++i) {
    int r = r0 + ty * 4 + i;
    us4 u4 = { f2bf(acc[i][0]), f2bf(acc[i][1]), f2bf(acc[i][2]), f2bf(acc[i][3]) };
    *(us4*)(outb + (size_t)r * 512 + cw0 + tx * 4) = u4;
  }
  if (isK) {
#pragma unroll
    for (int j = 0; j < 4; ++j) {
      int c = cw0 + tx * 4 + j;
      us4 u4 = { f2bf(acc[0][j]), f2bf(acc[1][j]), f2bf(acc[2][j]), f2bf(acc[3][j]) };
      *(us4*)(kT + ((size_t)(b * 512 + c)) * 2048 + l0 + ty * 4) = u4;
    }
  }
}

// ---------------------------------------------------------------- pass 1: denominators
// Per block: (b, 32 q, kk-split of 512), 8 waves = 8 heads. MFMA QK^T, exp,
// in-lane partial row sums, butterfly reduce -> lpart[b][sp][q][h].
__global__ __launch_bounds__(512) void pass1_kernel(
    const unsigned short* __restrict__ qb, const unsigned short* __restrict__ kb,
    float* __restrict__ lpart) {
  const int t = threadIdx.x;
  const int bid = blockIdx.x;          // ((b*64+qt)<<2)|sp
  const int sp = bid & 3;
  const int qt = (bid >> 2) & 63;
  const int b = bid >> 8;
  const int q0 = qt * 32;
  const int h = t >> 6;
  const int l = t & 63;
  const int row_lo = l & 15, kgrp = l >> 4;
  u16x8 qf[2][2];
  {
    const unsigned short* qbase = qb + ((size_t)(b * 2048 + q0 + row_lo)) * 512 + h * 64 + kgrp * 8;
    qf[0][0] = ldbf8(qbase);            qf[0][1] = ldbf8(qbase + 32);
    qf[1][0] = ldbf8(qbase + 16 * 512); qf[1][1] = ldbf8(qbase + 16 * 512 + 32);
  }
  float part[2][4] = {};
  const int kkb = sp * 512;
  for (int slab = 0; slab < 16; ++slab) {
    const int kk0 = kkb + slab * 32;
    const unsigned short* kbase = kb + ((size_t)(b * 2048 + kk0 + row_lo)) * 512 + h * 64 + kgrp * 8;
    u16x8 b00 = ldbf8(kbase);            u16x8 b01 = ldbf8(kbase + 32);
    u16x8 b10 = ldbf8(kbase + 16 * 512); u16x8 b11 = ldbf8(kbase + 16 * 512 + 32);
#pragma unroll
    for (int Mt = 0; Mt < 2; ++Mt) {
      f32x4 a0 = {0.f, 0.f, 0.f, 0.f}, a1 = {0.f, 0.f, 0.f, 0.f};
      a0 = mfma16(qf[Mt][0], b00, a0); a0 = mfma16(qf[Mt][1], b01, a0);
      a1 = mfma16(qf[Mt][0], b10, a1); a1 = mfma16(qf[Mt][1], b11, a1);
#pragma unroll
      for (int r = 0; r < 4; ++r)
        part[Mt][r] += __expf(a0[r] * 0.125f) + __expf(a1[r] * 0.125f);
    }
  }
#pragma unroll
  for (int Mt = 0; Mt < 2; ++Mt)
#pragma unroll
    for (int r = 0; r < 4; ++r) {
      float v = part[Mt][r];
      v += __shfl_xor(v, 1); v += __shfl_xor(v, 2);
      v += __shfl_xor(v, 4); v += __shfl_xor(v, 8);
      if (row_lo == 0)
        lpart[((size_t)((b * 4 + sp) * 2048) + q0 + Mt * 16 + kgrp * 4 + r) * 8 + h] = v;
    }
}

// ---------------------------------------------------------------- pass 2: attn + PV
// Recompute QK^T (identical MFMA order -> identical s), scale by 1/l, stage
// f32 attn slab in LDS [q][kk][h] for one coalesced write; bf16 P in padded
// LDS tile feeds PV MFMA against kT. dist partials per kk-split.
__global__ __launch_bounds__(512) void pass2_kernel(
    const unsigned short* __restrict__ qb, const unsigned short* __restrict__ kb,
    const unsigned short* __restrict__ kT, const float* __restrict__ lpart,
    float* __restrict__ attn, float* __restrict__ distp, int log2S) {
  __shared__ float Ps[32 * 32 * 8];           // [q][kk][h]  32 KB
  __shared__ unsigned short Pb[8 * 32 * 40];  // [h][q][kk(+8 pad)]  20 KB
  __shared__ float linv_s[32 * 8];
  const int t = threadIdx.x;
  const int bid = blockIdx.x;                 // ((b*64+qt)<<log2S)|sp
  const int S = 1 << log2S;
  const int sp = bid & (S - 1);
  const int qt = (bid >> log2S) & 63;
  const int b = bid >> (6 + log2S);
  const int q0 = qt * 32;
  if (t < 256) {
    int q = t >> 3, hh = t & 7;
    float s = 0.f;
#pragma unroll
    for (int p = 0; p < 4; ++p)
      s += lpart[((size_t)((b * 4 + p) * 2048) + q0 + q) * 8 + hh];
    linv_s[t] = 1.0f / s;
  }
  __syncthreads();
  const int h = t >> 6;
  const int l = t & 63;
  const int row_lo = l & 15, kgrp = l >> 4;
  u16x8 qf[2][2];
  {
    const unsigned short* qbase = qb + ((size_t)(b * 2048 + q0 + row_lo)) * 512 + h * 64 + kgrp * 8;
    qf[0][0] = ldbf8(qbase);            qf[0][1] = ldbf8(qbase + 32);
    qf[1][0] = ldbf8(qbase + 16 * 512); qf[1][1] = ldbf8(qbase + 16 * 512 + 32);
  }
  float lv[2][4];
#pragma unroll
  for (int Mt = 0; Mt < 2; ++Mt)
#pragma unroll
    for (int r = 0; r < 4; ++r)
      lv[Mt][r] = linv_s[(Mt * 16 + kgrp * 4 + r) * 8 + h];
  f32x4 dacc[2][4];
#pragma unroll
  for (int Mt = 0; Mt < 2; ++Mt)
#pragma unroll
    for (int Nd = 0; Nd < 4; ++Nd) dacc[Mt][Nd] = (f32x4){0.f, 0.f, 0.f, 0.f};

  const int nslab = 64 >> log2S;
  const int kkb = sp * (2048 >> log2S);
  for (int slab = 0; slab < nslab; ++slab) {
    const int kk0 = kkb + slab * 32;
    const unsigned short* kbase = kb + ((size_t)(b * 2048 + kk0 + row_lo)) * 512 + h * 64 + kgrp * 8;
    u16x8 b00 = ldbf8(kbase);            u16x8 b01 = ldbf8(kbase + 32);
    u16x8 b10 = ldbf8(kbase + 16 * 512); u16x8 b11 = ldbf8(kbase + 16 * 512 + 32);
#pragma unroll
    for (int Mt = 0; Mt < 2; ++Mt) {
      f32x4 a0 = {0.f, 0.f, 0.f, 0.f}, a1 = {0.f, 0.f, 0.f, 0.f};
      a0 = mfma16(qf[Mt][0], b00, a0); a0 = mfma16(qf[Mt][1], b01, a0);
      a1 = mfma16(qf[Mt][0], b10, a1); a1 = mfma16(qf[Mt][1], b11, a1);
#pragma unroll
      for (int r = 0; r < 4; ++r) {
        int q = Mt * 16 + kgrp * 4 + r;
        float e0 = __expf(a0[r] * 0.125f) * lv[Mt][r];
        float e1 = __expf(a1[r] * 0.125f) * lv[Mt][r];
        Ps[(q * 32 + row_lo) * 8 + h] = e0;
        Ps[(q * 32 + 16 + row_lo) * 8 + h] = e1;
        Pb[(h * 32 + q) * 40 + row_lo] = f2bf(e0);
        Pb[(h * 32 + q) * 40 + 16 + row_lo] = f2bf(e1);
      }
    }
    __syncthreads();
#pragma unroll
    for (int rep = 0; rep < 4; ++rep) {   // coalesced attn write: 32q x 32kk x 8h
      int idx = rep * 512 + t;
      int q = idx >> 6, u = idx & 63;
      float4 v = *(const float4*)&Ps[q * 256 + u * 4];
      *(float4*)(attn + ((size_t)(b * 2048 + q0 + q)) * (LSEQ * NH) + (size_t)kk0 * 8 + u * 4) = v;
    }
    // PV: dist[q][d] += P[q][kk] * K[kk][d], K from kT (lane-contiguous kk)
    u16x8 af0 = ldbf8(&Pb[(h * 32 + row_lo) * 40 + kgrp * 8]);
    u16x8 af1 = ldbf8(&Pb[(h * 32 + 16 + row_lo) * 40 + kgrp * 8]);
#pragma unroll
    for (int Nd = 0; Nd < 4; ++Nd) {
      u16x8 bv = ldbf8(kT + ((size_t)(b * 512 + h * 64 + Nd * 16 + row_lo)) * 2048 + kk0 + kgrp * 8);
      dacc[0][Nd] = mfma16(af0, bv, dacc[0][Nd]);
      dacc[1][Nd] = mfma16(af1, bv, dacc[1][Nd]);
    }
    __syncthreads();
  }
  float* dp = distp + (size_t)sp * (NB * LSEQ * DM);
#pragma unroll
  for (int Mt = 0; Mt < 2; ++Mt)
#pragma unroll
    for (int Nd = 0; Nd < 4; ++Nd)
#pragma unroll
      for (int r = 0; r < 4; ++r) {
        int q = q0 + Mt * 16 + kgrp * 4 + r;
        int d = h * 64 + Nd * 16 + row_lo;
        dp[((size_t)(b * 2048 + q)) * 512 + d] = dacc[Mt][Nd][r];
      }
}

// ---------------------------------------------------------------- combine dist partials
__global__ __launch_bounds__(256) void combine_kernel(const float* __restrict__ p,
                                                      float* __restrict__ dist, int S) {
  int i4 = blockIdx.x * 256 + threadIdx.x;
  const int N4 = (NB * LSEQ * DM) / 4;
  const float4* p4 = (const float4*)p;
  float4 s = p4[i4];
  for (int sp = 1; sp < S; ++sp) {
    float4 v = p4[(size_t)sp * N4 + i4];
    s.x += v.x; s.y += v.y; s.z += v.z; s.w += v.w;
  }
  ((float4*)dist)[i4] = s;
}

extern "C" void kernel_launch(void* const* d_in, const int* in_sizes, int n_in,
                              void* d_out, int out_size, void* d_ws, size_t ws_size,
                              hipStream_t stream) {
  const float* x  = (const float*)d_in[0];
  const float* Wq = (const float*)d_in[1];
  const float* bq = (const float*)d_in[2];
  const float* Wk = (const float*)d_in[3];
  const float* bk = (const float*)d_in[4];
  float* out  = (float*)d_out;
  float* dist = out;
  float* attn = out + (size_t)NB * LSEQ * DM;
  float* ws = (float*)d_ws;
  float* posT = ws;                                     // 1,048,576 f32
  float* lpart = ws + 1048576;                          //   131,072 f32
  unsigned short* qb = (unsigned short*)(ws + 1179648); // 4096x512 bf16
  unsigned short* kb = (unsigned short*)(ws + 2228224); // 4096x512 bf16
  unsigned short* kT = (unsigned short*)(ws + 3276800); // 2x512x2048 bf16
  float* distp = ws + 4325376;
  const size_t base_fl = 4325376;
  int log2S;
  if (ws_size >= (base_fl + 4ull * 2097152) * 4) log2S = 2;
  else if (ws_size >= (base_fl + 2ull * 2097152) * 4) log2S = 1;
  else log2S = 0;

  pos_kernel<<<4096, 256, 0, stream>>>(posT);
  proj_kernel<<<dim3(16, 64), 256, 0, stream>>>(x, posT, Wq, bq, Wk, bk, qb, kb, kT);
  pass1_kernel<<<512, 512, 0, stream>>>(qb, kb, lpart);
  float* dtarget = (log2S == 0) ? dist : distp;
  pass2_kernel<<<NB * 64 * (1 << log2S), 512, 0, stream>>>(qb, kb, kT, lpart, attn, dtarget, log2S);
  if (log2S)
    combine_kernel<<<2048, 256, 0, stream>>>(distp, dist, 1 << log2S);
}

// Round 4
// 178.949 us; speedup vs baseline: 3.3666x; 1.4075x over previous
//
#include <hip/hip_runtime.h>
#include <math.h>

constexpr int LSEQ = 2048;
constexpr int FEAT = 512;
constexpr int NH = 8;
constexpr int DM = 512;   // NH * HEAD_DIM
constexpr int NB = 2;

typedef __bf16 bf16x8 __attribute__((ext_vector_type(8)));
typedef unsigned short u16x8 __attribute__((ext_vector_type(8)));
typedef unsigned int u32x4 __attribute__((ext_vector_type(4)));
typedef float f32x4 __attribute__((ext_vector_type(4)));

__device__ inline f32x4 mfma16(u16x8 a, u16x8 b, f32x4 c) {
  return __builtin_amdgcn_mfma_f32_16x16x32_bf16(
      __builtin_bit_cast(bf16x8, a), __builtin_bit_cast(bf16x8, b), c, 0, 0, 0);
}
__device__ inline unsigned cvtpk(float lo, float hi) {  // [bf16(lo) | bf16(hi)<<16], RNE
  unsigned r;
  asm("v_cvt_pk_bf16_f32 %0, %1, %2" : "=v"(r) : "v"(lo), "v"(hi));
  return r;
}
__device__ inline u16x8 ldbf8(const unsigned short* p) {
  return *reinterpret_cast<const u16x8*>(p);
}

// ---------------------------------------------------------------- pos table
__global__ __launch_bounds__(256) void pos_kernel(float* __restrict__ posT) {
  int idx = blockIdx.x * 256 + threadIdx.x;   // f*LSEQ + l
  int l = idx & (LSEQ - 1);
  int f = idx >> 11;
  int i = f >> 1;
  double t = exp((double)i * (9.210340371976184 / 256.0));  // 10000^(i/256)
  float ang = (float)((double)l / t);
  posT[idx] = (f & 1) ? cosf(ang) : sinf(ang);
}

// ---------------------------------------------------------------- prep: abuf[r][f] = bf16(x^T + pos)
__global__ __launch_bounds__(256) void prep_kernel(const float* __restrict__ x,
                                                   const float* __restrict__ posT,
                                                   unsigned short* __restrict__ abuf) {
  __shared__ float As[64 * 68];
  const int t = threadIdx.x;
  const int bid = blockIdx.x;
  const int ft = bid & 7, lt = (bid >> 3) & 31, b = bid >> 8;
  const int f0 = ft * 64, l0 = lt * 64;
#pragma unroll
  for (int rep = 0; rep < 4; ++rep) {
    int fl = rep * 16 + (t >> 4), l4 = (t & 15) * 4;
    float4 xv = *(const float4*)(x + ((size_t)b * FEAT + f0 + fl) * LSEQ + l0 + l4);
    float4 pv = *(const float4*)(posT + (size_t)(f0 + fl) * LSEQ + l0 + l4);
    *(float4*)&As[fl * 68 + l4] = make_float4(xv.x + pv.x, xv.y + pv.y, xv.z + pv.z, xv.w + pv.w);
  }
  __syncthreads();
  const int ll = t >> 2, fc = t & 3;
#pragma unroll
  for (int rep = 0; rep < 4; ++rep) {
    int fb = (fc + rep * 4) * 4;
    float v0 = As[(fb + 0) * 68 + ll];
    float v1 = As[(fb + 1) * 68 + ll];
    float v2 = As[(fb + 2) * 68 + ll];
    float v3 = As[(fb + 3) * 68 + ll];
    uint2 u = make_uint2(cvtpk(v0, v1), cvtpk(v2, v3));
    *(uint2*)(abuf + ((size_t)(b * LSEQ + l0 + ll)) * 512 + f0 + fb) = u;
  }
}

// ---------------------------------------------------------------- W -> bf16 (rows 0-511 Wq, 512-1023 Wk)
__global__ __launch_bounds__(256) void wcvt_kernel(const float* __restrict__ Wq,
                                                   const float* __restrict__ Wk,
                                                   unsigned short* __restrict__ wbuf) {
  int i8 = blockIdx.x * 256 + threadIdx.x;   // 65536 total, 8 elems each
  size_t base = (size_t)i8 * 8;
  const float* src = (base < (size_t)512 * 512) ? Wq + base : Wk + (base - (size_t)512 * 512);
  float4 a = *(const float4*)src;
  float4 b4 = *(const float4*)(src + 4);
  *(uint2*)(wbuf + base) = make_uint2(cvtpk(a.x, a.y), cvtpk(a.z, a.w));
  *(uint2*)(wbuf + base + 4) = make_uint2(cvtpk(b4.x, b4.y), cvtpk(b4.z, b4.w));
}

// ---------------------------------------------------------------- proj: [q|k] = A @ W^T + b, bf16 MFMA
// Swapped operands: mfma(A=W rows c, B=abuf cols r) -> C[c][r]; lane owns 4 consecutive c.
__global__ __launch_bounds__(256) void proj_kernel(
    const unsigned short* __restrict__ abuf, const unsigned short* __restrict__ wbuf,
    const float* __restrict__ bq, const float* __restrict__ bk,
    unsigned short* __restrict__ qb, unsigned short* __restrict__ kb,
    unsigned short* __restrict__ kT) {
  const int t = threadIdx.x;
  const int c0 = blockIdx.x * 64;           // 0..960
  const int r0 = blockIdx.y * 64;           // 0..4032
  const int w = t >> 6, l = t & 63;
  const int lr = l & 15, g = l >> 4;
  const int c0w = c0 + (w >> 1) * 32;
  const int r0w = r0 + (w & 1) * 32;
  f32x4 acc[2][2];
#pragma unroll
  for (int i = 0; i < 2; ++i)
#pragma unroll
    for (int j = 0; j < 2; ++j) acc[i][j] = (f32x4){0.f, 0.f, 0.f, 0.f};
  for (int f0 = 0; f0 < FEAT; f0 += 32) {
    u16x8 a0 = ldbf8(wbuf + (size_t)(c0w + lr) * 512 + f0 + g * 8);
    u16x8 a1 = ldbf8(wbuf + (size_t)(c0w + 16 + lr) * 512 + f0 + g * 8);
    u16x8 b0 = ldbf8(abuf + (size_t)(r0w + lr) * 512 + f0 + g * 8);
    u16x8 b1 = ldbf8(abuf + (size_t)(r0w + 16 + lr) * 512 + f0 + g * 8);
    acc[0][0] = mfma16(a0, b0, acc[0][0]);
    acc[0][1] = mfma16(a0, b1, acc[0][1]);
    acc[1][0] = mfma16(a1, b0, acc[1][0]);
    acc[1][1] = mfma16(a1, b1, acc[1][1]);
  }
  const int isK = (c0 >= DM);
  const float* bias = isK ? bk : bq;
  unsigned short* ob = isK ? kb : qb;
  const int cb = c0w & (DM - 1);
#pragma unroll
  for (int ch = 0; ch < 2; ++ch) {
    int c = cb + ch * 16 + g * 4;
    float b0v = bias[c], b1v = bias[c + 1], b2v = bias[c + 2], b3v = bias[c + 3];
#pragma unroll
    for (int rh = 0; rh < 2; ++rh) {
      int r = r0w + rh * 16 + lr;
      f32x4 v = acc[ch][rh];
      uint2 u = make_uint2(cvtpk(v[0] + b0v, v[1] + b1v), cvtpk(v[2] + b2v, v[3] + b3v));
      *(uint2*)(ob + (size_t)r * 512 + c) = u;
      if (isK) {
        int bsel = r >> 11, lq = r & (LSEQ - 1);
        unsigned short* kp = kT + ((size_t)(bsel * 512 + c)) * 2048 + lq;
        kp[0] = (unsigned short)(u.x & 0xffff);
        kp[2048] = (unsigned short)(u.x >> 16);
        kp[2 * 2048] = (unsigned short)(u.y & 0xffff);
        kp[3 * 2048] = (unsigned short)(u.y >> 16);
      }
    }
  }
}

// ---------------------------------------------------------------- pass 1: softmax denominators
// Swapped QK^T (A=K, B=Q): lane owns one q column; in-lane exp-sum, 2-step shuffle reduce.
__global__ __launch_bounds__(512) void pass1_kernel(
    const unsigned short* __restrict__ qb, const unsigned short* __restrict__ kb,
    float* __restrict__ lpart) {
  const int t = threadIdx.x;
  const int bid = blockIdx.x;
  const int sp = bid & 3, qt = (bid >> 2) & 63, b = bid >> 8;
  const int q0 = qt * 32;
  const int h = t >> 6, l = t & 63;
  const int lr = l & 15, g = l >> 4;
  u16x8 qf[2][2];
#pragma unroll
  for (int Mt = 0; Mt < 2; ++Mt)
#pragma unroll
    for (int dh = 0; dh < 2; ++dh)
      qf[Mt][dh] = ldbf8(qb + (size_t)(b * LSEQ + q0 + Mt * 16 + lr) * 512 + h * 64 + dh * 32 + g * 8);
  float sum[2] = {0.f, 0.f};
  for (int slab = 0; slab < 16; ++slab) {
    const int kk0 = sp * 512 + slab * 32;
    u16x8 af[2][2];
#pragma unroll
    for (int kh = 0; kh < 2; ++kh)
#pragma unroll
      for (int dh = 0; dh < 2; ++dh)
        af[kh][dh] = ldbf8(kb + (size_t)(b * LSEQ + kk0 + kh * 16 + lr) * 512 + h * 64 + dh * 32 + g * 8);
#pragma unroll
    for (int Mt = 0; Mt < 2; ++Mt)
#pragma unroll
      for (int kh = 0; kh < 2; ++kh) {
        f32x4 s = (f32x4){0.f, 0.f, 0.f, 0.f};
        s = mfma16(af[kh][0], qf[Mt][0], s);
        s = mfma16(af[kh][1], qf[Mt][1], s);
        sum[Mt] += __expf(s[0] * 0.125f) + __expf(s[1] * 0.125f) +
                   __expf(s[2] * 0.125f) + __expf(s[3] * 0.125f);
      }
  }
#pragma unroll
  for (int Mt = 0; Mt < 2; ++Mt) {
    float v = sum[Mt];
    v += __shfl_xor(v, 16);
    v += __shfl_xor(v, 32);
    if ((l & 48) == 0)
      lpart[((size_t)((b * 4 + sp) * LSEQ) + q0 + Mt * 16 + lr) * 8 + h] = v;
  }
}

// ---------------------------------------------------------------- pass 2: attn write + PV
// Recompute QK^T swapped, normalize, stage Ps[q][h][kk] f32 (one tile feeds both the
// coalesced attn write and the PV A-fragments via cvt_pk).
__global__ __launch_bounds__(512) void pass2_kernel(
    const unsigned short* __restrict__ qb, const unsigned short* __restrict__ kb,
    const unsigned short* __restrict__ kT, const float* __restrict__ lpart,
    float* __restrict__ attn, float* __restrict__ distp, int log2S) {
  __shared__ float Ps[32 * 292];   // [q][h*36 + kk], q-stride 292 (b128-aligned)
  __shared__ float linv[256];
  const int t = threadIdx.x;
  const int bid = blockIdx.x;
  const int S = 1 << log2S;
  const int sp = bid & (S - 1);
  const int qt = (bid >> log2S) & 63;
  const int b = bid >> (6 + log2S);
  const int q0 = qt * 32;
  if (t < 256) {
    int q = t >> 3, hh = t & 7;
    float s = 0.f;
#pragma unroll
    for (int p = 0; p < 4; ++p)
      s += lpart[((size_t)((b * 4 + p) * LSEQ) + q0 + q) * 8 + hh];
    linv[t] = 1.0f / s;
  }
  __syncthreads();
  const int h = t >> 6, l = t & 63;
  const int lr = l & 15, g = l >> 4;
  u16x8 qf[2][2];
#pragma unroll
  for (int Mt = 0; Mt < 2; ++Mt)
#pragma unroll
    for (int dh = 0; dh < 2; ++dh)
      qf[Mt][dh] = ldbf8(qb + (size_t)(b * LSEQ + q0 + Mt * 16 + lr) * 512 + h * 64 + dh * 32 + g * 8);
  float lv[2] = {linv[lr * 8 + h], linv[(16 + lr) * 8 + h]};
  f32x4 dacc[2][4];
#pragma unroll
  for (int Mt = 0; Mt < 2; ++Mt)
#pragma unroll
    for (int Nd = 0; Nd < 4; ++Nd) dacc[Mt][Nd] = (f32x4){0.f, 0.f, 0.f, 0.f};

  const int nslab = 64 >> log2S;
  const int kkb = sp * (2048 >> log2S);
  for (int slab = 0; slab < nslab; ++slab) {
    const int kk0 = kkb + slab * 32;
    u16x8 af[2][2];
#pragma unroll
    for (int kh = 0; kh < 2; ++kh)
#pragma unroll
      for (int dh = 0; dh < 2; ++dh)
        af[kh][dh] = ldbf8(kb + (size_t)(b * LSEQ + kk0 + kh * 16 + lr) * 512 + h * 64 + dh * 32 + g * 8);
    u16x8 bt[4];
#pragma unroll
    for (int Nd = 0; Nd < 4; ++Nd)
      bt[Nd] = ldbf8(kT + (size_t)(b * 512 + h * 64 + Nd * 16 + lr) * 2048 + kk0 + g * 8);
#pragma unroll
    for (int Mt = 0; Mt < 2; ++Mt)
#pragma unroll
      for (int kh = 0; kh < 2; ++kh) {
        f32x4 s = (f32x4){0.f, 0.f, 0.f, 0.f};
        s = mfma16(af[kh][0], qf[Mt][0], s);
        s = mfma16(af[kh][1], qf[Mt][1], s);
        float e0 = __expf(s[0] * 0.125f) * lv[Mt];
        float e1 = __expf(s[1] * 0.125f) * lv[Mt];
        float e2 = __expf(s[2] * 0.125f) * lv[Mt];
        float e3 = __expf(s[3] * 0.125f) * lv[Mt];
        int base = (Mt * 16 + lr) * 292 + h * 36 + kh * 16 + g * 4;
        *(float2*)&Ps[base] = make_float2(e0, e1);
        *(float2*)&Ps[base + 2] = make_float2(e2, e3);
      }
    __syncthreads();
#pragma unroll
    for (int rep = 0; rep < 4; ++rep) {   // coalesced attn write: 32q x 32kk x 8h
      int F = rep * 512 + t;
      int q = F >> 6, kk = (F >> 1) & 31, hh = (F & 1) * 4;
      int pb = q * 292 + hh * 36 + kk;
      float4 v = make_float4(Ps[pb], Ps[pb + 36], Ps[pb + 72], Ps[pb + 108]);
      *(float4*)(attn + ((size_t)(b * LSEQ + q0 + q)) * (LSEQ * NH) + (size_t)(kk0 + kk) * 8 + hh) = v;
    }
#pragma unroll
    for (int Mt = 0; Mt < 2; ++Mt) {   // PV from normalized Ps
      int pb = (Mt * 16 + lr) * 292 + h * 36 + g * 8;
      f32x4 plo = *(const f32x4*)&Ps[pb];
      f32x4 phi = *(const f32x4*)&Ps[pb + 4];
      u32x4 pu = {cvtpk(plo[0], plo[1]), cvtpk(plo[2], plo[3]),
                  cvtpk(phi[0], phi[1]), cvtpk(phi[2], phi[3])};
      u16x8 pa = __builtin_bit_cast(u16x8, pu);
#pragma unroll
      for (int Nd = 0; Nd < 4; ++Nd)
        dacc[Mt][Nd] = mfma16(pa, bt[Nd], dacc[Mt][Nd]);
    }
    __syncthreads();
  }
  float* dp = distp + (size_t)sp * (NB * LSEQ * DM);
#pragma unroll
  for (int Mt = 0; Mt < 2; ++Mt)
#pragma unroll
    for (int Nd = 0; Nd < 4; ++Nd)
#pragma unroll
      for (int r = 0; r < 4; ++r)
        dp[((size_t)(b * LSEQ + q0 + Mt * 16 + g * 4 + r)) * 512 + h * 64 + Nd * 16 + lr] =
            dacc[Mt][Nd][r];
}

// ---------------------------------------------------------------- combine (S=2)
__global__ __launch_bounds__(256) void combine_kernel(const float* __restrict__ p,
                                                      float* __restrict__ dist) {
  int i4 = blockIdx.x * 256 + threadIdx.x;
  const int N4 = (NB * LSEQ * DM) / 4;
  const float4* p4 = (const float4*)p;
  float4 a = p4[i4], c = p4[N4 + i4];
  ((float4*)dist)[i4] = make_float4(a.x + c.x, a.y + c.y, a.z + c.z, a.w + c.w);
}

extern "C" void kernel_launch(void* const* d_in, const int* in_sizes, int n_in,
                              void* d_out, int out_size, void* d_ws, size_t ws_size,
                              hipStream_t stream) {
  const float* x  = (const float*)d_in[0];
  const float* Wq = (const float*)d_in[1];
  const float* bq = (const float*)d_in[2];
  const float* Wk = (const float*)d_in[3];
  const float* bk = (const float*)d_in[4];
  float* out  = (float*)d_out;
  float* dist = out;
  float* attn = out + (size_t)NB * LSEQ * DM;
  float* ws = (float*)d_ws;
  float* posT  = ws;                                     // 1,048,576 f32
  float* lpart = ws + 1048576;                           //   131,072 f32
  unsigned short* abuf = (unsigned short*)(ws + 1179648);  // 4096x512 bf16
  unsigned short* wbuf = (unsigned short*)(ws + 2228224);  // 1024x512 bf16
  unsigned short* qb   = (unsigned short*)(ws + 2490368);  // 4096x512 bf16
  unsigned short* kb   = (unsigned short*)(ws + 3538944);  // 4096x512 bf16
  unsigned short* kT   = (unsigned short*)(ws + 4587520);  // 2x512x2048 bf16
  float* distp = ws + 5636096;
  const int log2S = (ws_size >= (size_t)(5636096 + 2ull * 2097152) * 4) ? 1 : 0;

  pos_kernel<<<4096, 256, 0, stream>>>(posT);
  prep_kernel<<<512, 256, 0, stream>>>(x, posT, abuf);
  wcvt_kernel<<<256, 256, 0, stream>>>(Wq, Wk, wbuf);
  proj_kernel<<<dim3(16, 64), 256, 0, stream>>>(abuf, wbuf, bq, bk, qb, kb, kT);
  pass1_kernel<<<512, 512, 0, stream>>>(qb, kb, lpart);
  float* dtarget = (log2S == 0) ? dist : distp;
  pass2_kernel<<<NB * 64 * (1 << log2S), 512, 0, stream>>>(qb, kb, kT, lpart, attn, dtarget, log2S);
  if (log2S)
    combine_kernel<<<2048, 256, 0, stream>>>(distp, dist);
}

// Round 6
// 177.895 us; speedup vs baseline: 3.3865x; 1.0059x over previous
//
#include <hip/hip_runtime.h>
#include <math.h>

constexpr int LSEQ = 2048;
constexpr int FEAT = 512;
constexpr int NH = 8;
constexpr int DM = 512;   // NH * HEAD_DIM
constexpr int NB = 2;

typedef __bf16 bf16x8 __attribute__((ext_vector_type(8)));
typedef unsigned short u16x8 __attribute__((ext_vector_type(8)));
typedef unsigned int u32x4 __attribute__((ext_vector_type(4)));
typedef float f32x4 __attribute__((ext_vector_type(4)));

#define EXPC 0.18033688011112042f   // log2(e)/8

__device__ inline f32x4 mfma16(u16x8 a, u16x8 b, f32x4 c) {
  return __builtin_amdgcn_mfma_f32_16x16x32_bf16(
      __builtin_bit_cast(bf16x8, a), __builtin_bit_cast(bf16x8, b), c, 0, 0, 0);
}
__device__ inline unsigned cvtpk(float lo, float hi) {  // [bf16(lo) | bf16(hi)<<16], RNE
  unsigned r;
  asm("v_cvt_pk_bf16_f32 %0, %1, %2" : "=v"(r) : "v"(lo), "v"(hi));
  return r;
}
__device__ inline u16x8 ldbf8(const unsigned short* p) {
  return *reinterpret_cast<const u16x8*>(p);
}

// ---------------------------------------------------------------- pos table
__global__ __launch_bounds__(256) void pos_kernel(float* __restrict__ posT) {
  int idx = blockIdx.x * 256 + threadIdx.x;   // f*LSEQ + l
  int l = idx & (LSEQ - 1);
  int f = idx >> 11;
  int i = f >> 1;
  double t = exp((double)i * (9.210340371976184 / 256.0));  // 10000^(i/256)
  float ang = (float)((double)l / t);
  posT[idx] = (f & 1) ? cosf(ang) : sinf(ang);
}

// ---------------------------------------------------------------- prep: abuf[r][f] = bf16(x^T + pos)
__global__ __launch_bounds__(256) void prep_kernel(const float* __restrict__ x,
                                                   const float* __restrict__ posT,
                                                   unsigned short* __restrict__ abuf) {
  __shared__ float As[64 * 68];
  const int t = threadIdx.x;
  const int bid = blockIdx.x;
  const int ft = bid & 7, lt = (bid >> 3) & 31, b = bid >> 8;
  const int f0 = ft * 64, l0 = lt * 64;
#pragma unroll
  for (int rep = 0; rep < 4; ++rep) {
    int fl = rep * 16 + (t >> 4), l4 = (t & 15) * 4;
    float4 xv = *(const float4*)(x + ((size_t)b * FEAT + f0 + fl) * LSEQ + l0 + l4);
    float4 pv = *(const float4*)(posT + (size_t)(f0 + fl) * LSEQ + l0 + l4);
    *(float4*)&As[fl * 68 + l4] = make_float4(xv.x + pv.x, xv.y + pv.y, xv.z + pv.z, xv.w + pv.w);
  }
  __syncthreads();
  const int ll = t >> 2, fc = t & 3;
#pragma unroll
  for (int rep = 0; rep < 4; ++rep) {
    int fb = (fc + rep * 4) * 4;
    float v0 = As[(fb + 0) * 68 + ll];
    float v1 = As[(fb + 1) * 68 + ll];
    float v2 = As[(fb + 2) * 68 + ll];
    float v3 = As[(fb + 3) * 68 + ll];
    uint2 u = make_uint2(cvtpk(v0, v1), cvtpk(v2, v3));
    *(uint2*)(abuf + ((size_t)(b * LSEQ + l0 + ll)) * 512 + f0 + fb) = u;
  }
}

// ---------------------------------------------------------------- W -> bf16 (rows 0-511 Wq, 512-1023 Wk)
__global__ __launch_bounds__(256) void wcvt_kernel(const float* __restrict__ Wq,
                                                   const float* __restrict__ Wk,
                                                   unsigned short* __restrict__ wbuf) {
  int i8 = blockIdx.x * 256 + threadIdx.x;   // 65536 total, 8 elems each
  size_t base = (size_t)i8 * 8;
  const float* src = (base < (size_t)512 * 512) ? Wq + base : Wk + (base - (size_t)512 * 512);
  float4 a = *(const float4*)src;
  float4 b4 = *(const float4*)(src + 4);
  *(uint2*)(wbuf + base) = make_uint2(cvtpk(a.x, a.y), cvtpk(a.z, a.w));
  *(uint2*)(wbuf + base + 4) = make_uint2(cvtpk(b4.x, b4.y), cvtpk(b4.z, b4.w));
}

// ---------------------------------------------------------------- proj: [q|k] = A @ W^T + b, bf16 MFMA
// Swapped operands: mfma(A=W rows c, B=abuf cols r) -> C[c][r]; lane owns 4 consecutive c.
__global__ __launch_bounds__(256) void proj_kernel(
    const unsigned short* __restrict__ abuf, const unsigned short* __restrict__ wbuf,
    const float* __restrict__ bq, const float* __restrict__ bk,
    unsigned short* __restrict__ qb, unsigned short* __restrict__ kb,
    unsigned short* __restrict__ kT) {
  const int t = threadIdx.x;
  const int c0 = blockIdx.x * 64;           // 0..960
  const int r0 = blockIdx.y * 64;           // 0..4032
  const int w = t >> 6, l = t & 63;
  const int lr = l & 15, g = l >> 4;
  const int c0w = c0 + (w >> 1) * 32;
  const int r0w = r0 + (w & 1) * 32;
  f32x4 acc[2][2];
#pragma unroll
  for (int i = 0; i < 2; ++i)
#pragma unroll
    for (int j = 0; j < 2; ++j) acc[i][j] = (f32x4){0.f, 0.f, 0.f, 0.f};
  for (int f0 = 0; f0 < FEAT; f0 += 32) {
    u16x8 a0 = ldbf8(wbuf + (size_t)(c0w + lr) * 512 + f0 + g * 8);
    u16x8 a1 = ldbf8(wbuf + (size_t)(c0w + 16 + lr) * 512 + f0 + g * 8);
    u16x8 b0 = ldbf8(abuf + (size_t)(r0w + lr) * 512 + f0 + g * 8);
    u16x8 b1 = ldbf8(abuf + (size_t)(r0w + 16 + lr) * 512 + f0 + g * 8);
    acc[0][0] = mfma16(a0, b0, acc[0][0]);
    acc[0][1] = mfma16(a0, b1, acc[0][1]);
    acc[1][0] = mfma16(a1, b0, acc[1][0]);
    acc[1][1] = mfma16(a1, b1, acc[1][1]);
  }
  const int isK = (c0 >= DM);
  const float* bias = isK ? bk : bq;
  unsigned short* ob = isK ? kb : qb;
  const int cb = c0w & (DM - 1);
#pragma unroll
  for (int ch = 0; ch < 2; ++ch) {
    int c = cb + ch * 16 + g * 4;
    float b0v = bias[c], b1v = bias[c + 1], b2v = bias[c + 2], b3v = bias[c + 3];
#pragma unroll
    for (int rh = 0; rh < 2; ++rh) {
      int r = r0w + rh * 16 + lr;
      f32x4 v = acc[ch][rh];
      uint2 u = make_uint2(cvtpk(v[0] + b0v, v[1] + b1v), cvtpk(v[2] + b2v, v[3] + b3v));
      *(uint2*)(ob + (size_t)r * 512 + c) = u;
      if (isK) {
        int bsel = r >> 11, lq = r & (LSEQ - 1);
        unsigned short* kp = kT + ((size_t)(bsel * 512 + c)) * 2048 + lq;
        kp[0] = (unsigned short)(u.x & 0xffff);
        kp[2048] = (unsigned short)(u.x >> 16);
        kp[2 * 2048] = (unsigned short)(u.y & 0xffff);
        kp[3 * 2048] = (unsigned short)(u.y >> 16);
      }
    }
  }
}

// ---------------------------------------------------------------- pass 1: softmax denominators
// Swapped QK^T (A=K, B=Q): lane owns one q column; in-lane exp-sum, 2-step shuffle reduce.
__global__ __launch_bounds__(512, 4) void pass1_kernel(
    const unsigned short* __restrict__ qb, const unsigned short* __restrict__ kb,
    float* __restrict__ lpart) {
  const int t = threadIdx.x;
  const int bid = blockIdx.x;
  const int sp = bid & 3, qt = (bid >> 2) & 63, b = bid >> 8;
  const int q0 = qt * 32;
  const int h = t >> 6, l = t & 63;
  const int lr = l & 15, g = l >> 4;
  u16x8 qf[2][2];
#pragma unroll
  for (int Mt = 0; Mt < 2; ++Mt)
#pragma unroll
    for (int dh = 0; dh < 2; ++dh)
      qf[Mt][dh] = ldbf8(qb + (size_t)(b * LSEQ + q0 + Mt * 16 + lr) * 512 + h * 64 + dh * 32 + g * 8);
  float sum[2] = {0.f, 0.f};
  for (int slab = 0; slab < 16; ++slab) {
    const int kk0 = sp * 512 + slab * 32;
    u16x8 af[2][2];
#pragma unroll
    for (int kh = 0; kh < 2; ++kh)
#pragma unroll
      for (int dh = 0; dh < 2; ++dh)
        af[kh][dh] = ldbf8(kb + (size_t)(b * LSEQ + kk0 + kh * 16 + lr) * 512 + h * 64 + dh * 32 + g * 8);
#pragma unroll
    for (int Mt = 0; Mt < 2; ++Mt)
#pragma unroll
      for (int kh = 0; kh < 2; ++kh) {
        f32x4 s = (f32x4){0.f, 0.f, 0.f, 0.f};
        s = mfma16(af[kh][0], qf[Mt][0], s);
        s = mfma16(af[kh][1], qf[Mt][1], s);
        sum[Mt] += exp2f(s[0] * EXPC) + exp2f(s[1] * EXPC) +
                   exp2f(s[2] * EXPC) + exp2f(s[3] * EXPC);
      }
  }
#pragma unroll
  for (int Mt = 0; Mt < 2; ++Mt) {
    float v = sum[Mt];
    v += __shfl_xor(v, 16);
    v += __shfl_xor(v, 32);
    if ((l & 48) == 0)
      lpart[((size_t)((b * 4 + sp) * LSEQ) + q0 + Mt * 16 + lr) * 8 + h] = v;
  }
}

// ---------------------------------------------------------------- pass 2: attn write + PV
// Recompute QK^T swapped, normalize, stage Ps[q][h][kk] f32 (one tile feeds both the
// coalesced attn write and the PV A-fragments via cvt_pk).
__global__ __launch_bounds__(512, 4) void pass2_kernel(
    const unsigned short* __restrict__ qb, const unsigned short* __restrict__ kb,
    const unsigned short* __restrict__ kT, const float* __restrict__ lpart,
    float* __restrict__ attn, float* __restrict__ distp, int log2S) {
  __shared__ float Ps[32 * 292];   // [q][h*36 + kk], q-stride 292 (b128-aligned)
  __shared__ float linv[256];
  const int t = threadIdx.x;
  const int bid = blockIdx.x;
  const int S = 1 << log2S;
  const int sp = bid & (S - 1);
  const int qt = (bid >> log2S) & 63;
  const int b = bid >> (6 + log2S);
  const int q0 = qt * 32;
  if (t < 256) {
    int q = t >> 3, hh = t & 7;
    float s = 0.f;
#pragma unroll
    for (int p = 0; p < 4; ++p)
      s += lpart[((size_t)((b * 4 + p) * LSEQ) + q0 + q) * 8 + hh];
    linv[t] = 1.0f / s;
  }
  __syncthreads();
  const int h = t >> 6, l = t & 63;
  const int lr = l & 15, g = l >> 4;
  u16x8 qf[2][2];
#pragma unroll
  for (int Mt = 0; Mt < 2; ++Mt)
#pragma unroll
    for (int dh = 0; dh < 2; ++dh)
      qf[Mt][dh] = ldbf8(qb + (size_t)(b * LSEQ + q0 + Mt * 16 + lr) * 512 + h * 64 + dh * 32 + g * 8);
  float lv[2] = {linv[lr * 8 + h], linv[(16 + lr) * 8 + h]};
  f32x4 dacc[2][4];
#pragma unroll
  for (int Mt = 0; Mt < 2; ++Mt)
#pragma unroll
    for (int Nd = 0; Nd < 4; ++Nd) dacc[Mt][Nd] = (f32x4){0.f, 0.f, 0.f, 0.f};

  const int nslab = 64 >> log2S;
  const int kkb = sp * (2048 >> log2S);
  for (int slab = 0; slab < nslab; ++slab) {
    const int kk0 = kkb + slab * 32;
    u16x8 af[2][2];
#pragma unroll
    for (int kh = 0; kh < 2; ++kh)
#pragma unroll
      for (int dh = 0; dh < 2; ++dh)
        af[kh][dh] = ldbf8(kb + (size_t)(b * LSEQ + kk0 + kh * 16 + lr) * 512 + h * 64 + dh * 32 + g * 8);
    u16x8 bt[4];
#pragma unroll
    for (int Nd = 0; Nd < 4; ++Nd)
      bt[Nd] = ldbf8(kT + (size_t)(b * 512 + h * 64 + Nd * 16 + lr) * 2048 + kk0 + g * 8);
#pragma unroll
    for (int Mt = 0; Mt < 2; ++Mt)
#pragma unroll
      for (int kh = 0; kh < 2; ++kh) {
        f32x4 s = (f32x4){0.f, 0.f, 0.f, 0.f};
        s = mfma16(af[kh][0], qf[Mt][0], s);
        s = mfma16(af[kh][1], qf[Mt][1], s);
        float e0 = exp2f(s[0] * EXPC) * lv[Mt];
        float e1 = exp2f(s[1] * EXPC) * lv[Mt];
        float e2 = exp2f(s[2] * EXPC) * lv[Mt];
        float e3 = exp2f(s[3] * EXPC) * lv[Mt];
        int base = (Mt * 16 + lr) * 292 + h * 36 + kh * 16 + g * 4;
        *(float2*)&Ps[base] = make_float2(e0, e1);
        *(float2*)&Ps[base + 2] = make_float2(e2, e3);
      }
    __syncthreads();
#pragma unroll
    for (int rep = 0; rep < 4; ++rep) {   // coalesced attn write: 32q x 32kk x 8h
      int F = rep * 512 + t;
      int q = F >> 6, kk = (F >> 1) & 31, hh = (F & 1) * 4;
      int pb = q * 292 + hh * 36 + kk;
      f32x4 v = {Ps[pb], Ps[pb + 36], Ps[pb + 72], Ps[pb + 108]};
      __builtin_nontemporal_store(v,
          (f32x4*)(attn + ((size_t)(b * LSEQ + q0 + q)) * (LSEQ * NH) + (size_t)(kk0 + kk) * 8 + hh));
    }
#pragma unroll
    for (int Mt = 0; Mt < 2; ++Mt) {   // PV from normalized Ps
      int pb = (Mt * 16 + lr) * 292 + h * 36 + g * 8;
      f32x4 plo = *(const f32x4*)&Ps[pb];
      f32x4 phi = *(const f32x4*)&Ps[pb + 4];
      u32x4 pu = {cvtpk(plo[0], plo[1]), cvtpk(plo[2], plo[3]),
                  cvtpk(phi[0], phi[1]), cvtpk(phi[2], phi[3])};
      u16x8 pa = __builtin_bit_cast(u16x8, pu);
#pragma unroll
      for (int Nd = 0; Nd < 4; ++Nd)
        dacc[Mt][Nd] = mfma16(pa, bt[Nd], dacc[Mt][Nd]);
    }
    __syncthreads();
  }
  float* dp = distp + (size_t)sp * (NB * LSEQ * DM);
#pragma unroll
  for (int Mt = 0; Mt < 2; ++Mt)
#pragma unroll
    for (int Nd = 0; Nd < 4; ++Nd)
#pragma unroll
      for (int r = 0; r < 4; ++r)
        dp[((size_t)(b * LSEQ + q0 + Mt * 16 + g * 4 + r)) * 512 + h * 64 + Nd * 16 + lr] =
            dacc[Mt][Nd][r];
}

// ---------------------------------------------------------------- combine dist partials
__global__ __launch_bounds__(256) void combine_kernel(const float* __restrict__ p,
                                                      float* __restrict__ dist, int S) {
  int i4 = blockIdx.x * 256 + threadIdx.x;
  const int N4 = (NB * LSEQ * DM) / 4;
  const float4* p4 = (const float4*)p;
  float4 s = p4[i4];
  for (int sp = 1; sp < S; ++sp) {
    float4 v = p4[(size_t)sp * N4 + i4];
    s.x += v.x; s.y += v.y; s.z += v.z; s.w += v.w;
  }
  ((float4*)dist)[i4] = s;
}

extern "C" void kernel_launch(void* const* d_in, const int* in_sizes, int n_in,
                              void* d_out, int out_size, void* d_ws, size_t ws_size,
                              hipStream_t stream) {
  const float* x  = (const float*)d_in[0];
  const float* Wq = (const float*)d_in[1];
  const float* bq = (const float*)d_in[2];
  const float* Wk = (const float*)d_in[3];
  const float* bk = (const float*)d_in[4];
  float* out  = (float*)d_out;
  float* dist = out;
  float* attn = out + (size_t)NB * LSEQ * DM;
  float* ws = (float*)d_ws;
  float* posT  = ws;                                     // 1,048,576 f32
  float* lpart = ws + 1048576;                           //   131,072 f32
  unsigned short* abuf = (unsigned short*)(ws + 1179648);  // 4096x512 bf16
  unsigned short* wbuf = (unsigned short*)(ws + 2228224);  // 1024x512 bf16
  unsigned short* qb   = (unsigned short*)(ws + 2490368);  // 4096x512 bf16
  unsigned short* kb   = (unsigned short*)(ws + 3538944);  // 4096x512 bf16
  unsigned short* kT   = (unsigned short*)(ws + 4587520);  // 2x512x2048 bf16
  float* distp = ws + 5636096;
  int log2S;
  if (ws_size >= (size_t)(5636096 + 4ull * 2097152) * 4) log2S = 2;
  else if (ws_size >= (size_t)(5636096 + 2ull * 2097152) * 4) log2S = 1;
  else log2S = 0;

  pos_kernel<<<4096, 256, 0, stream>>>(posT);
  prep_kernel<<<512, 256, 0, stream>>>(x, posT, abuf);
  wcvt_kernel<<<256, 256, 0, stream>>>(Wq, Wk, wbuf);
  proj_kernel<<<dim3(16, 64), 256, 0, stream>>>(abuf, wbuf, bq, bk, qb, kb, kT);
  pass1_kernel<<<512, 512, 0, stream>>>(qb, kb, lpart);
  float* dtarget = (log2S == 0) ? dist : distp;
  pass2_kernel<<<NB * 64 * (1 << log2S), 512, 0, stream>>>(qb, kb, kT, lpart, attn, dtarget, log2S);
  if (log2S)
    combine_kernel<<<2048, 256, 0, stream>>>(distp, dist, 1 << log2S);
}

// Round 7
// 162.642 us; speedup vs baseline: 3.7041x; 1.0938x over previous
//
#include <hip/hip_runtime.h>
#include <math.h>

constexpr int LSEQ = 2048;
constexpr int FEAT = 512;
constexpr int NH = 8;
constexpr int DM = 512;   // NH * HEAD_DIM
constexpr int NB = 2;

typedef __bf16 bf16x8 __attribute__((ext_vector_type(8)));
typedef unsigned short u16x8 __attribute__((ext_vector_type(8)));
typedef unsigned int u32x4 __attribute__((ext_vector_type(4)));
typedef float f32x4 __attribute__((ext_vector_type(4)));

#define EXPC 0.18033688011112042f   // log2(e)/8

__device__ inline f32x4 mfma16(u16x8 a, u16x8 b, f32x4 c) {
  return __builtin_amdgcn_mfma_f32_16x16x32_bf16(
      __builtin_bit_cast(bf16x8, a), __builtin_bit_cast(bf16x8, b), c, 0, 0, 0);
}
__device__ inline unsigned cvtpk(float lo, float hi) {  // [bf16(lo) | bf16(hi)<<16], RNE
  unsigned r;
  asm("v_cvt_pk_bf16_f32 %0, %1, %2" : "=v"(r) : "v"(lo), "v"(hi));
  return r;
}
__device__ inline u16x8 ldbf8(const unsigned short* p) {
  return *reinterpret_cast<const u16x8*>(p);
}

// ---------------------------------------------------------------- pos table
__global__ __launch_bounds__(256) void pos_kernel(float* __restrict__ posT) {
  int idx = blockIdx.x * 256 + threadIdx.x;   // f*LSEQ + l
  int l = idx & (LSEQ - 1);
  int f = idx >> 11;
  int i = f >> 1;
  double t = exp((double)i * (9.210340371976184 / 256.0));  // 10000^(i/256)
  float ang = (float)((double)l / t);
  posT[idx] = (f & 1) ? cosf(ang) : sinf(ang);
}

// ---------------------------------------------------------------- prep: abuf[r][f] = bf16(x^T + pos)
__global__ __launch_bounds__(256) void prep_kernel(const float* __restrict__ x,
                                                   const float* __restrict__ posT,
                                                   unsigned short* __restrict__ abuf) {
  __shared__ float As[64 * 68];
  const int t = threadIdx.x;
  const int bid = blockIdx.x;
  const int ft = bid & 7, lt = (bid >> 3) & 31, b = bid >> 8;
  const int f0 = ft * 64, l0 = lt * 64;
#pragma unroll
  for (int rep = 0; rep < 4; ++rep) {
    int fl = rep * 16 + (t >> 4), l4 = (t & 15) * 4;
    float4 xv = *(const float4*)(x + ((size_t)b * FEAT + f0 + fl) * LSEQ + l0 + l4);
    float4 pv = *(const float4*)(posT + (size_t)(f0 + fl) * LSEQ + l0 + l4);
    *(float4*)&As[fl * 68 + l4] = make_float4(xv.x + pv.x, xv.y + pv.y, xv.z + pv.z, xv.w + pv.w);
  }
  __syncthreads();
  const int ll = t >> 2, fc = t & 3;
#pragma unroll
  for (int rep = 0; rep < 4; ++rep) {
    int fb = (fc + rep * 4) * 4;
    float v0 = As[(fb + 0) * 68 + ll];
    float v1 = As[(fb + 1) * 68 + ll];
    float v2 = As[(fb + 2) * 68 + ll];
    float v3 = As[(fb + 3) * 68 + ll];
    uint2 u = make_uint2(cvtpk(v0, v1), cvtpk(v2, v3));
    *(uint2*)(abuf + ((size_t)(b * LSEQ + l0 + ll)) * 512 + f0 + fb) = u;
  }
}

// ---------------------------------------------------------------- W -> bf16 (rows 0-511 Wq, 512-1023 Wk)
__global__ __launch_bounds__(256) void wcvt_kernel(const float* __restrict__ Wq,
                                                   const float* __restrict__ Wk,
                                                   unsigned short* __restrict__ wbuf) {
  int i8 = blockIdx.x * 256 + threadIdx.x;   // 65536 total, 8 elems each
  size_t base = (size_t)i8 * 8;
  const float* src = (base < (size_t)512 * 512) ? Wq + base : Wk + (base - (size_t)512 * 512);
  float4 a = *(const float4*)src;
  float4 b4 = *(const float4*)(src + 4);
  *(uint2*)(wbuf + base) = make_uint2(cvtpk(a.x, a.y), cvtpk(a.z, a.w));
  *(uint2*)(wbuf + base + 4) = make_uint2(cvtpk(b4.x, b4.y), cvtpk(b4.z, b4.w));
}

// ---------------------------------------------------------------- proj: [q|k] = A @ W^T + b, bf16 MFMA
__global__ __launch_bounds__(256) void proj_kernel(
    const unsigned short* __restrict__ abuf, const unsigned short* __restrict__ wbuf,
    const float* __restrict__ bq, const float* __restrict__ bk,
    unsigned short* __restrict__ qb, unsigned short* __restrict__ kb,
    unsigned short* __restrict__ kT) {
  const int t = threadIdx.x;
  const int c0 = blockIdx.x * 64;           // 0..960
  const int r0 = blockIdx.y * 64;           // 0..4032
  const int w = t >> 6, l = t & 63;
  const int lr = l & 15, g = l >> 4;
  const int c0w = c0 + (w >> 1) * 32;
  const int r0w = r0 + (w & 1) * 32;
  f32x4 acc[2][2];
#pragma unroll
  for (int i = 0; i < 2; ++i)
#pragma unroll
    for (int j = 0; j < 2; ++j) acc[i][j] = (f32x4){0.f, 0.f, 0.f, 0.f};
  for (int f0 = 0; f0 < FEAT; f0 += 32) {
    u16x8 a0 = ldbf8(wbuf + (size_t)(c0w + lr) * 512 + f0 + g * 8);
    u16x8 a1 = ldbf8(wbuf + (size_t)(c0w + 16 + lr) * 512 + f0 + g * 8);
    u16x8 b0 = ldbf8(abuf + (size_t)(r0w + lr) * 512 + f0 + g * 8);
    u16x8 b1 = ldbf8(abuf + (size_t)(r0w + 16 + lr) * 512 + f0 + g * 8);
    acc[0][0] = mfma16(a0, b0, acc[0][0]);
    acc[0][1] = mfma16(a0, b1, acc[0][1]);
    acc[1][0] = mfma16(a1, b0, acc[1][0]);
    acc[1][1] = mfma16(a1, b1, acc[1][1]);
  }
  const int isK = (c0 >= DM);
  const float* bias = isK ? bk : bq;
  unsigned short* ob = isK ? kb : qb;
  const int cb = c0w & (DM - 1);
#pragma unroll
  for (int ch = 0; ch < 2; ++ch) {
    int c = cb + ch * 16 + g * 4;
    float b0v = bias[c], b1v = bias[c + 1], b2v = bias[c + 2], b3v = bias[c + 3];
#pragma unroll
    for (int rh = 0; rh < 2; ++rh) {
      int r = r0w + rh * 16 + lr;
      f32x4 v = acc[ch][rh];
      uint2 u = make_uint2(cvtpk(v[0] + b0v, v[1] + b1v), cvtpk(v[2] + b2v, v[3] + b3v));
      *(uint2*)(ob + (size_t)r * 512 + c) = u;
      if (isK) {
        int bsel = r >> 11, lq = r & (LSEQ - 1);
        unsigned short* kp = kT + ((size_t)(bsel * 512 + c)) * 2048 + lq;
        kp[0] = (unsigned short)(u.x & 0xffff);
        kp[2048] = (unsigned short)(u.x >> 16);
        kp[2 * 2048] = (unsigned short)(u.y & 0xffff);
        kp[3 * 2048] = (unsigned short)(u.y >> 16);
      }
    }
  }
}

// ---------------------------------------------------------------- pass 1: softmax denominators
// QT=64 (Mt=4), kk-split S1=8 -> grid 512. Swapped QK^T: lane col = q.
__global__ __launch_bounds__(512) void pass1_kernel(
    const unsigned short* __restrict__ qb, const unsigned short* __restrict__ kb,
    float* __restrict__ lpart) {
  const int t = threadIdx.x;
  const int bid = blockIdx.x;
  const int sp = bid & 7, qt = (bid >> 3) & 31, b = bid >> 8;
  const int q0 = qt * 64;
  const int h = t >> 6, l = t & 63;
  const int lr = l & 15, g = l >> 4;
  u16x8 qf[4][2];
#pragma unroll
  for (int Mt = 0; Mt < 4; ++Mt)
#pragma unroll
    for (int dh = 0; dh < 2; ++dh)
      qf[Mt][dh] = ldbf8(qb + (size_t)(b * LSEQ + q0 + Mt * 16 + lr) * 512 + h * 64 + dh * 32 + g * 8);
  float sum[4] = {0.f, 0.f, 0.f, 0.f};
  for (int slab = 0; slab < 8; ++slab) {
    const int kk0 = sp * 256 + slab * 32;
    u16x8 af[2][2];
#pragma unroll
    for (int kh = 0; kh < 2; ++kh)
#pragma unroll
      for (int dh = 0; dh < 2; ++dh)
        af[kh][dh] = ldbf8(kb + (size_t)(b * LSEQ + kk0 + kh * 16 + lr) * 512 + h * 64 + dh * 32 + g * 8);
#pragma unroll
    for (int Mt = 0; Mt < 4; ++Mt)
#pragma unroll
      for (int kh = 0; kh < 2; ++kh) {
        f32x4 s = (f32x4){0.f, 0.f, 0.f, 0.f};
        s = mfma16(af[kh][0], qf[Mt][0], s);
        s = mfma16(af[kh][1], qf[Mt][1], s);
        sum[Mt] += exp2f(s[0] * EXPC) + exp2f(s[1] * EXPC) +
                   exp2f(s[2] * EXPC) + exp2f(s[3] * EXPC);
      }
  }
#pragma unroll
  for (int Mt = 0; Mt < 4; ++Mt) {
    float v = sum[Mt];
    v += __shfl_xor(v, 16);
    v += __shfl_xor(v, 32);
    if ((l & 48) == 0)
      lpart[((size_t)((b * 8 + sp) * LSEQ) + q0 + Mt * 16 + lr) * 8 + h] = v;
  }
}

// ---------------------------------------------------------------- pass 2: attn write + PV
// QT=64 (Mt=4), kk-split S (grid NB*32*S). Ps[64][292] f32 feeds attn write + PV.
__global__ __launch_bounds__(512) void pass2_kernel(
    const unsigned short* __restrict__ qb, const unsigned short* __restrict__ kb,
    const unsigned short* __restrict__ kT, const float* __restrict__ lpart,
    float* __restrict__ attn, float* __restrict__ distp, int log2S) {
  __shared__ float Ps[64 * 292];   // [q][h*36 + kk], 74.75 KB
  __shared__ float linv[512];
  const int t = threadIdx.x;
  const int bid = blockIdx.x;
  const int S = 1 << log2S;
  const int sp = bid & (S - 1);
  const int qt = (bid >> log2S) & 31;
  const int b = bid >> (5 + log2S);
  const int q0 = qt * 64;
  {
    int q = t >> 3, hh = t & 7;
    float s = 0.f;
#pragma unroll
    for (int p = 0; p < 8; ++p)
      s += lpart[((size_t)((b * 8 + p) * LSEQ) + q0 + q) * 8 + hh];
    linv[t] = 1.0f / s;
  }
  __syncthreads();
  const int h = t >> 6, l = t & 63;
  const int lr = l & 15, g = l >> 4;
  u16x8 qf[4][2];
#pragma unroll
  for (int Mt = 0; Mt < 4; ++Mt)
#pragma unroll
    for (int dh = 0; dh < 2; ++dh)
      qf[Mt][dh] = ldbf8(qb + (size_t)(b * LSEQ + q0 + Mt * 16 + lr) * 512 + h * 64 + dh * 32 + g * 8);
  float lv[4];
#pragma unroll
  for (int Mt = 0; Mt < 4; ++Mt) lv[Mt] = linv[(Mt * 16 + lr) * 8 + h];
  f32x4 dacc[4][4];
#pragma unroll
  for (int Mt = 0; Mt < 4; ++Mt)
#pragma unroll
    for (int Nd = 0; Nd < 4; ++Nd) dacc[Mt][Nd] = (f32x4){0.f, 0.f, 0.f, 0.f};

  const int nslab = 64 >> log2S;
  const int kkb = sp * (2048 >> log2S);
  for (int slab = 0; slab < nslab; ++slab) {
    const int kk0 = kkb + slab * 32;
    u16x8 af[2][2];
#pragma unroll
    for (int kh = 0; kh < 2; ++kh)
#pragma unroll
      for (int dh = 0; dh < 2; ++dh)
        af[kh][dh] = ldbf8(kb + (size_t)(b * LSEQ + kk0 + kh * 16 + lr) * 512 + h * 64 + dh * 32 + g * 8);
    u16x8 bt[4];
#pragma unroll
    for (int Nd = 0; Nd < 4; ++Nd)
      bt[Nd] = ldbf8(kT + (size_t)(b * 512 + h * 64 + Nd * 16 + lr) * 2048 + kk0 + g * 8);
#pragma unroll
    for (int Mt = 0; Mt < 4; ++Mt)
#pragma unroll
      for (int kh = 0; kh < 2; ++kh) {
        f32x4 s = (f32x4){0.f, 0.f, 0.f, 0.f};
        s = mfma16(af[kh][0], qf[Mt][0], s);
        s = mfma16(af[kh][1], qf[Mt][1], s);
        float e0 = exp2f(s[0] * EXPC) * lv[Mt];
        float e1 = exp2f(s[1] * EXPC) * lv[Mt];
        float e2 = exp2f(s[2] * EXPC) * lv[Mt];
        float e3 = exp2f(s[3] * EXPC) * lv[Mt];
        int base = (Mt * 16 + lr) * 292 + h * 36 + kh * 16 + g * 4;
        *(float2*)&Ps[base] = make_float2(e0, e1);
        *(float2*)&Ps[base + 2] = make_float2(e2, e3);
      }
    __syncthreads();
#pragma unroll
    for (int rep = 0; rep < 8; ++rep) {   // coalesced attn write: 64q x 32kk x 8h
      int F = rep * 512 + t;
      int q = F >> 6, kk = (F >> 1) & 31, hh = (F & 1) * 4;
      int pb = q * 292 + hh * 36 + kk;
      f32x4 v = {Ps[pb], Ps[pb + 36], Ps[pb + 72], Ps[pb + 108]};
      __builtin_nontemporal_store(v,
          (f32x4*)(attn + ((size_t)(b * LSEQ + q0 + q)) * (LSEQ * NH) + (size_t)(kk0 + kk) * 8 + hh));
    }
#pragma unroll
    for (int Mt = 0; Mt < 4; ++Mt) {   // PV from normalized Ps
      int pb = (Mt * 16 + lr) * 292 + h * 36 + g * 8;
      f32x4 plo = *(const f32x4*)&Ps[pb];
      f32x4 phi = *(const f32x4*)&Ps[pb + 4];
      u32x4 pu = {cvtpk(plo[0], plo[1]), cvtpk(plo[2], plo[3]),
                  cvtpk(phi[0], phi[1]), cvtpk(phi[2], phi[3])};
      u16x8 pa = __builtin_bit_cast(u16x8, pu);
#pragma unroll
      for (int Nd = 0; Nd < 4; ++Nd)
        dacc[Mt][Nd] = mfma16(pa, bt[Nd], dacc[Mt][Nd]);
    }
    __syncthreads();
  }
  float* dp = distp + (size_t)sp * (NB * LSEQ * DM);
#pragma unroll
  for (int Mt = 0; Mt < 4; ++Mt)
#pragma unroll
    for (int Nd = 0; Nd < 4; ++Nd)
#pragma unroll
      for (int r = 0; r < 4; ++r)
        dp[((size_t)(b * LSEQ + q0 + Mt * 16 + g * 4 + r)) * 512 + h * 64 + Nd * 16 + lr] =
            dacc[Mt][Nd][r];
}

// ---------------------------------------------------------------- combine dist partials
__global__ __launch_bounds__(256) void combine_kernel(const float* __restrict__ p,
                                                      float* __restrict__ dist, int S) {
  int i4 = blockIdx.x * 256 + threadIdx.x;
  const int N4 = (NB * LSEQ * DM) / 4;
  const float4* p4 = (const float4*)p;
  float4 s = p4[i4];
  for (int sp = 1; sp < S; ++sp) {
    float4 v = p4[(size_t)sp * N4 + i4];
    s.x += v.x; s.y += v.y; s.z += v.z; s.w += v.w;
  }
  ((float4*)dist)[i4] = s;
}

extern "C" void kernel_launch(void* const* d_in, const int* in_sizes, int n_in,
                              void* d_out, int out_size, void* d_ws, size_t ws_size,
                              hipStream_t stream) {
  const float* x  = (const float*)d_in[0];
  const float* Wq = (const float*)d_in[1];
  const float* bq = (const float*)d_in[2];
  const float* Wk = (const float*)d_in[3];
  const float* bk = (const float*)d_in[4];
  float* out  = (float*)d_out;
  float* dist = out;
  float* attn = out + (size_t)NB * LSEQ * DM;
  float* ws = (float*)d_ws;
  float* posT  = ws;                                       // 1,048,576 f32
  float* lpart = ws + 1048576;                             //   262,144 f32 (8 splits)
  unsigned short* abuf = (unsigned short*)(ws + 1310720);  // 4096x512 bf16
  unsigned short* wbuf = (unsigned short*)(ws + 2359296);  // 1024x512 bf16
  unsigned short* qb   = (unsigned short*)(ws + 2621440);  // 4096x512 bf16
  unsigned short* kb   = (unsigned short*)(ws + 3670016);  // 4096x512 bf16
  unsigned short* kT   = (unsigned short*)(ws + 4718592);  // 2x512x2048 bf16
  float* distp = ws + 5767168;
  int log2S;
  if (ws_size >= (size_t)(5767168 + 4ull * 2097152) * 4) log2S = 2;
  else if (ws_size >= (size_t)(5767168 + 2ull * 2097152) * 4) log2S = 1;
  else log2S = 0;

  pos_kernel<<<4096, 256, 0, stream>>>(posT);
  prep_kernel<<<512, 256, 0, stream>>>(x, posT, abuf);
  wcvt_kernel<<<256, 256, 0, stream>>>(Wq, Wk, wbuf);
  proj_kernel<<<dim3(16, 64), 256, 0, stream>>>(abuf, wbuf, bq, bk, qb, kb, kT);
  pass1_kernel<<<512, 512, 0, stream>>>(qb, kb, lpart);
  float* dtarget = (log2S == 0) ? dist : distp;
  pass2_kernel<<<NB * 32 * (1 << log2S), 512, 0, stream>>>(qb, kb, kT, lpart, attn, dtarget, log2S);
  if (log2S)
    combine_kernel<<<2048, 256, 0, stream>>>(distp, dist, 1 << log2S);
}